// Round 1
// baseline (82.050 us; speedup 1.0000x reference)
//
#include <hip/hip_runtime.h>
#include <hip/hip_bf16.h>

// Problem constants (match reference)
#define BB 16384
#define DD 512
#define NCLS 90
#define KC 32

typedef __attribute__((ext_vector_type(8))) short short8;   // 8 bf16 (4 VGPRs)
typedef __attribute__((ext_vector_type(4))) float fx4;      // MFMA accumulator

static __device__ __forceinline__ short f2bf(float f) {
    unsigned u = __float_as_uint(f);
    unsigned r = (u + 0x7fffu + ((u >> 16) & 1u)) >> 16;    // RNE
    return (short)r;
}

// ---------------- kernel 1: center row inverse norms (2880 rows) --------------
__global__ void k_cinv(const float* __restrict__ centers, float* __restrict__ cinv) {
    int row = blockIdx.x * 4 + (threadIdx.x >> 6);          // 720 blocks x 4 waves
    int lane = threadIdx.x & 63;
    const float4* p = (const float4*)(centers + (size_t)row * DD);
    float4 a = p[lane * 2];
    float4 b = p[lane * 2 + 1];
    float s = a.x * a.x + a.y * a.y + a.z * a.z + a.w * a.w
            + b.x * b.x + b.y * b.y + b.z * b.z + b.w * b.w;
#pragma unroll
    for (int m = 1; m < 64; m <<= 1) s += __shfl_xor(s, m, 64);
    if (lane == 0) cinv[row] = rsqrtf(s + 1e-12f);
}

// ---------------- kernel 2: histogram + exclusive scan (1 block) --------------
__global__ void k_hist_scan(const int* __restrict__ labels,
                            int* __restrict__ offsets, int* __restrict__ cursors) {
    __shared__ int h[NCLS];
    int t = threadIdx.x;
    if (t < NCLS) h[t] = 0;
    __syncthreads();
    for (int i = t; i < BB; i += 256) atomicAdd(&h[labels[i]], 1);
    __syncthreads();
    if (t == 0) {
        int acc = 0;
        for (int c = 0; c < NCLS; c++) {
            offsets[c] = acc;
            cursors[c] = acc;
            acc += h[c];
        }
        offsets[NCLS] = acc;
    }
}

// ---------------- kernel 3: scatter sample indices into class buckets ---------
__global__ void k_scatter(const int* __restrict__ labels,
                          int* __restrict__ cursors, int* __restrict__ idx) {
    int i = blockIdx.x * 256 + threadIdx.x;
    int c = labels[i];
    int pos = atomicAdd(&cursors[c], 1);
    idx[pos] = i;
}

// ---------------- kernel 4: main — bucketed MFMA + softmax loss ---------------
// grid = 90 classes * 8 p-blocks, block = 256 (4 waves)
__launch_bounds__(256, 2)
__global__ void k_main(const float* __restrict__ x,
                       const float* __restrict__ centers,
                       const float* __restrict__ cinv,
                       const int* __restrict__ offsets,
                       const int* __restrict__ idx,
                       float* __restrict__ per_sample) {
    __shared__ __align__(16) short c_lds[KC * DD];   // 32 KiB, bf16, XOR-swizzled
    __shared__ __align__(16) short x_lds[32 * DD];   // 32 KiB, bf16, XOR-swizzled
    __shared__ float S_lds[32][33];
    __shared__ float xinv[32];

    int c = blockIdx.x >> 3;
    int p = blockIdx.x & 7;
    int off = offsets[c];
    int cnt = offsets[c + 1] - off;
    int nch = (cnt + 31) >> 5;
    if (p >= nch) return;

    int t = threadIdx.x;
    int row = t >> 3;       // 0..31 (8 threads per row)
    int l8 = t & 7;

    // ---- stage this class's 32 normalized center rows (bf16, swizzled) ----
    {
        float sc = cinv[c * KC + row];
        const float4* src = (const float4*)(centers + ((size_t)c * KC + row) * DD);
#pragma unroll
        for (int j = 0; j < 8; j++) {
            int c16 = l8 + 8 * j;                       // 16B chunk index, 0..63
            float4 a = src[c16 * 2], b = src[c16 * 2 + 1];
            short8 v;
            v[0] = f2bf(a.x * sc); v[1] = f2bf(a.y * sc);
            v[2] = f2bf(a.z * sc); v[3] = f2bf(a.w * sc);
            v[4] = f2bf(b.x * sc); v[5] = f2bf(b.y * sc);
            v[6] = f2bf(b.z * sc); v[7] = f2bf(b.w * sc);
            *(short8*)&c_lds[row * DD + ((c16 ^ (row & 7)) << 3)] = v;
        }
    }

    int w = t >> 6, lane = t & 63;
    int mrow = ((w & 1) << 4) + (lane & 15);
    int nrow = ((w >> 1) << 4) + (lane & 15);

    for (int ch = p; ch < nch; ch += 8) {
        int base = off + (ch << 5);
        int rem = cnt - (ch << 5);                      // > 0

        // ---- stage 32 x-rows (raw bf16, swizzled) + per-row norms ----
        {
            int g = (row < rem) ? idx[base + row] : -1;
            const float4* src = (g >= 0) ? (const float4*)(x + (size_t)g * DD) : (const float4*)x;
            float nrm = 0.f;
#pragma unroll
            for (int j = 0; j < 8; j++) {
                int c16 = l8 + 8 * j;
                float4 a = {0, 0, 0, 0}, b = {0, 0, 0, 0};
                if (g >= 0) { a = src[c16 * 2]; b = src[c16 * 2 + 1]; }
                nrm += a.x * a.x + a.y * a.y + a.z * a.z + a.w * a.w
                     + b.x * b.x + b.y * b.y + b.z * b.z + b.w * b.w;
                short8 v;
                v[0] = f2bf(a.x); v[1] = f2bf(a.y); v[2] = f2bf(a.z); v[3] = f2bf(a.w);
                v[4] = f2bf(b.x); v[5] = f2bf(b.y); v[6] = f2bf(b.z); v[7] = f2bf(b.w);
                *(short8*)&x_lds[row * DD + ((c16 ^ (row & 7)) << 3)] = v;
            }
#pragma unroll
            for (int m = 1; m < 8; m <<= 1) nrm += __shfl_xor(nrm, m, 64);
            if (l8 == 0) xinv[row] = rsqrtf(nrm + 1e-12f);
        }
        __syncthreads();

        // ---- MFMA: S[32 samples][32 k] in 4 wave-quadrants ----
        fx4 acc = {0.f, 0.f, 0.f, 0.f};
#pragma unroll
        for (int ks = 0; ks < 16; ks++) {
            int c16a = ks * 4 + (lane >> 4);
            short8 av = *(const short8*)&x_lds[mrow * DD + ((c16a ^ (mrow & 7)) << 3)];
            short8 bv = *(const short8*)&c_lds[nrow * DD + ((c16a ^ (nrow & 7)) << 3)];
            acc = __builtin_amdgcn_mfma_f32_16x16x32_bf16(av, bv, acc, 0, 0, 0);
        }
#pragma unroll
        for (int j = 0; j < 4; j++) {
            int r = ((w & 1) << 4) + ((lane >> 4) << 2) + j;   // C/D: row=(lane>>4)*4+reg
            int col = ((w >> 1) << 4) + (lane & 15);           //      col=lane&15
            S_lds[r][col] = acc[j];
        }
        __syncthreads();

        // ---- softmax over K=32 + per-sample loss; 8 threads per row ----
        {
            float xv = xinv[row];
            int q = l8 << 2;                                  // k quarter base
            float s0 = S_lds[row][q + 0] * xv;
            float s1 = S_lds[row][q + 1] * xv;
            float s2 = S_lds[row][q + 2] * xv;
            float s3 = S_lds[row][q + 3] * xv;
            float mx = fmaxf(fmaxf(s0, s1), fmaxf(s2, s3));
#pragma unroll
            for (int m = 1; m < 8; m <<= 1) mx = fmaxf(mx, __shfl_xor(mx, m, 64));
            float e0 = expf(s0 - mx), e1 = expf(s1 - mx);
            float e2 = expf(s2 - mx), e3 = expf(s3 - mx);
            float Z = e0 + e1 + e2 + e3;
            float num = e0 * (1.f - s0) + e1 * (1.f - s1) + e2 * (1.f - s2) + e3 * (1.f - s3);
#pragma unroll
            for (int m = 1; m < 8; m <<= 1) {
                Z += __shfl_xor(Z, m, 64);
                num += __shfl_xor(num, m, 64);
            }
            if (l8 == 0 && row < rem) per_sample[idx[base + row]] = num / Z;
        }
        __syncthreads();   // protect x_lds/S_lds before next chunk
    }
}

// ---------------- kernel 5: deterministic mean reduction ----------------------
__global__ void k_reduce(const float* __restrict__ per_sample, float* __restrict__ out) {
    __shared__ float red[256];
    int t = threadIdx.x;
    float s = 0.f;
    for (int i = t; i < BB; i += 256) s += per_sample[i];
    red[t] = s;
    __syncthreads();
    for (int h = 128; h > 0; h >>= 1) {
        if (t < h) red[t] += red[t + h];
        __syncthreads();
    }
    if (t == 0) out[0] = red[0] / (float)BB;
}

extern "C" void kernel_launch(void* const* d_in, const int* in_sizes, int n_in,
                              void* d_out, int out_size, void* d_ws, size_t ws_size,
                              hipStream_t stream) {
    const float* x       = (const float*)d_in[0];
    const int*   labels  = (const int*)d_in[1];
    const float* centers = (const float*)d_in[2];
    float* out = (float*)d_out;

    char* ws = (char*)d_ws;
    int*   offsets = (int*)(ws + 0);               // 91 ints
    int*   cursors = (int*)(ws + 512);             // 90 ints
    float* cinv    = (float*)(ws + 1024);          // 2880 floats
    int*   idx     = (int*)(ws + 16384);           // 16384 ints
    float* pers    = (float*)(ws + 16384 + 65536); // 16384 floats

    k_cinv<<<NCLS * KC / 4, 256, 0, stream>>>(centers, cinv);            // 720 blocks
    k_hist_scan<<<1, 256, 0, stream>>>(labels, offsets, cursors);
    k_scatter<<<BB / 256, 256, 0, stream>>>(labels, cursors, idx);
    k_main<<<NCLS * 8, 256, 0, stream>>>(x, centers, cinv, offsets, idx, pers);
    k_reduce<<<1, 256, 0, stream>>>(pers, out);
}

// Round 2
// 41.195 us; speedup vs baseline: 1.9917x; 1.9917x over previous
//
#include <hip/hip_runtime.h>
#include <hip/hip_bf16.h>

// Problem constants (match reference)
#define BB 16384
#define DD 512
#define NCLS 90
#define KC 32
#define BUCKET 512   // max samples per class slot (mean 182, >24 sigma headroom)

typedef __attribute__((ext_vector_type(8))) short short8;   // 8 bf16 (4 VGPRs)
typedef __attribute__((ext_vector_type(4))) float fx4;      // MFMA accumulator

static __device__ __forceinline__ short f2bf(float f) {
    unsigned u = __float_as_uint(f);
    unsigned r = (u + 0x7fffu + ((u >> 16) & 1u)) >> 16;    // RNE
    return (short)r;
}

static __device__ __forceinline__ void gload_lds16(const void* g, void* l) {
    __builtin_amdgcn_global_load_lds(
        (const __attribute__((address_space(1))) void*)g,
        (__attribute__((address_space(3))) void*)l, 16, 0, 0);
}

// ------- kernel 1: normalize x AND centers -> bf16 images (one wave per row) --
// rows 0..BB-1 are x, rows BB..BB+2879 are centers. 19264 rows / 4 per block.
__global__ void k_norm(const float* __restrict__ x, const float* __restrict__ centers,
                       short* __restrict__ xn, short* __restrict__ cni) {
    int row = blockIdx.x * 4 + (threadIdx.x >> 6);
    int lane = threadIdx.x & 63;
    const float* src;
    short* dst;
    if (row < BB) {
        src = x + (size_t)row * DD;
        dst = xn + (size_t)row * DD;
    } else {
        int r = row - BB;
        src = centers + (size_t)r * DD;
        dst = cni + (size_t)r * DD;
    }
    const float4* p = (const float4*)src;
    float4 a = p[lane * 2];
    float4 b = p[lane * 2 + 1];
    float s = a.x * a.x + a.y * a.y + a.z * a.z + a.w * a.w
            + b.x * b.x + b.y * b.y + b.z * b.z + b.w * b.w;
#pragma unroll
    for (int m = 1; m < 64; m <<= 1) s += __shfl_xor(s, m, 64);
    float sc = rsqrtf(s + 1e-12f);
    short8 v;
    v[0] = f2bf(a.x * sc); v[1] = f2bf(a.y * sc);
    v[2] = f2bf(a.z * sc); v[3] = f2bf(a.w * sc);
    v[4] = f2bf(b.x * sc); v[5] = f2bf(b.y * sc);
    v[6] = f2bf(b.z * sc); v[7] = f2bf(b.w * sc);
    *(short8*)(dst + lane * 8) = v;
}

// ------- kernel 2: deterministic ballot-compaction binning (1 block / class) --
// Two passes over labels, no atomics. Bucket c occupies idx[c*BUCKET ...].
__global__ void k_bin(const int* __restrict__ labels,
                      int* __restrict__ idx, int* __restrict__ cnt) {
    __shared__ int wcnt[4];
    int c = blockIdx.x;
    int t = threadIdx.x, w = t >> 6, lane = t & 63;
    int seg = w * (BB / 4);
    // pass 1: per-wave segment count
    int cw = 0;
    for (int j = lane; j < BB / 4; j += 64) cw += (labels[seg + j] == c);
#pragma unroll
    for (int m = 1; m < 64; m <<= 1) cw += __shfl_xor(cw, m, 64);
    if (lane == 0) wcnt[w] = cw;
    __syncthreads();
    int pos = c * BUCKET;
    for (int ww = 0; ww < w; ww++) pos += wcnt[ww];
    // pass 2: emit in ascending-index order (deterministic)
    for (int j = lane; j < BB / 4; j += 64) {
        bool m = (labels[seg + j] == c);
        unsigned long long mask = __ballot(m);
        if (m) idx[pos + __popcll(mask & ((1ull << lane) - 1ull))] = seg + j;
        pos += __popcll(mask);
    }
    if (t == 0) cnt[c] = wcnt[0] + wcnt[1] + wcnt[2] + wcnt[3];
}

// ------- kernel 3: main — bucketed MFMA + softmax loss -----------------------
// grid = 90 classes * 8 p-blocks, block = 256 (4 waves). All staging via
// global_load_lds width=16 with pre-swizzled SOURCE (LDS dest linear).
__launch_bounds__(256, 2)
__global__ void k_main(const short* __restrict__ xn,
                       const short* __restrict__ cni,
                       const int* __restrict__ cnt,
                       const int* __restrict__ idx,
                       float* __restrict__ per_sample) {
    __shared__ __align__(16) short c_lds[KC * DD];   // 32 KiB bf16, XOR-swizzled
    __shared__ __align__(16) short x_lds[32 * DD];   // 32 KiB bf16, XOR-swizzled
    __shared__ float S_lds[32][33];

    int c = blockIdx.x >> 3;
    int p = blockIdx.x & 7;
    int n = cnt[c];
    int nch = (n + 31) >> 5;
    if (p >= nch) return;

    int t = threadIdx.x, w = t >> 6, lane = t & 63;

    // ---- stage this class's 32 normalized center rows (8 x gload_lds16) ----
    const short* cbase = cni + (size_t)c * KC * DD;
#pragma unroll
    for (int it = 0; it < 8; it++) {
        int q = t + 256 * it;                 // 16B chunk 0..2047 (linear LDS)
        int drow = q >> 6, cc = q & 63;
        int scc = cc ^ (drow & 7);            // swizzle applied on SOURCE
        gload_lds16(cbase + drow * DD + scc * 8, &c_lds[q * 8]);
    }

    int base = c * BUCKET;
    int mrow = ((w & 1) << 4) + (lane & 15);
    int nrow = ((w >> 1) << 4) + (lane & 15);
    int row8 = t >> 3, l8 = t & 7;            // softmax: 8 threads per row

    for (int ch = p; ch < nch; ch += 8) {
        int off = ch << 5;
        int rem = n - off;                    // > 0

        // ---- stage 32 gathered x rows (8 x gload_lds16; row is wave-uniform)
#pragma unroll
        for (int it = 0; it < 8; it++) {
            int q = t + 256 * it;
            int drow = q >> 6, cc = q & 63;   // drow = w + 4*it (wave-uniform)
            int r = (drow < rem) ? drow : (rem - 1);
            int g = idx[base + off + r];
            int scc = cc ^ (drow & 7);
            gload_lds16(xn + (size_t)g * DD + scc * 8, &x_lds[q * 8]);
        }
        __syncthreads();

        // ---- MFMA: S[32 samples][32 k] in 4 wave-quadrants ----
        fx4 acc = {0.f, 0.f, 0.f, 0.f};
#pragma unroll
        for (int ks = 0; ks < 16; ks++) {
            int c16a = ks * 4 + (lane >> 4);
            short8 av = *(const short8*)&x_lds[mrow * DD + ((c16a ^ (mrow & 7)) << 3)];
            short8 bv = *(const short8*)&c_lds[nrow * DD + ((c16a ^ (nrow & 7)) << 3)];
            acc = __builtin_amdgcn_mfma_f32_16x16x32_bf16(av, bv, acc, 0, 0, 0);
        }
#pragma unroll
        for (int j = 0; j < 4; j++) {
            int r = ((w & 1) << 4) + ((lane >> 4) << 2) + j;   // C/D row
            int col = ((w >> 1) << 4) + (lane & 15);           // C/D col
            S_lds[r][col] = acc[j];
        }
        __syncthreads();

        // ---- softmax over K=32 + per-sample loss; 8 threads per row ----
        {
            int q4 = l8 << 2;
            float s0 = S_lds[row8][q4 + 0];
            float s1 = S_lds[row8][q4 + 1];
            float s2 = S_lds[row8][q4 + 2];
            float s3 = S_lds[row8][q4 + 3];
            float mx = fmaxf(fmaxf(s0, s1), fmaxf(s2, s3));
#pragma unroll
            for (int m = 1; m < 8; m <<= 1) mx = fmaxf(mx, __shfl_xor(mx, m, 64));
            float e0 = expf(s0 - mx), e1 = expf(s1 - mx);
            float e2 = expf(s2 - mx), e3 = expf(s3 - mx);
            float Z = e0 + e1 + e2 + e3;
            float num = e0 * (1.f - s0) + e1 * (1.f - s1)
                      + e2 * (1.f - s2) + e3 * (1.f - s3);
#pragma unroll
            for (int m = 1; m < 8; m <<= 1) {
                Z += __shfl_xor(Z, m, 64);
                num += __shfl_xor(num, m, 64);
            }
            if (l8 == 0 && row8 < rem) per_sample[idx[base + off + row8]] = num / Z;
        }
        __syncthreads();   // protect x_lds/S_lds before next chunk
    }
}

// ------- kernel 4: deterministic mean reduction (1024 threads, float4) -------
__global__ void k_reduce(const float* __restrict__ per_sample, float* __restrict__ out) {
    __shared__ float red[1024];
    int t = threadIdx.x;
    const float4* p = (const float4*)per_sample;
    float s = 0.f;
    for (int i = t; i < BB / 4; i += 1024) {
        float4 v = p[i];
        s += v.x + v.y + v.z + v.w;
    }
    red[t] = s;
    __syncthreads();
    for (int h = 512; h > 0; h >>= 1) {
        if (t < h) red[t] += red[t + h];
        __syncthreads();
    }
    if (t == 0) out[0] = red[0] * (1.0f / (float)BB);
}

extern "C" void kernel_launch(void* const* d_in, const int* in_sizes, int n_in,
                              void* d_out, int out_size, void* d_ws, size_t ws_size,
                              hipStream_t stream) {
    const float* x       = (const float*)d_in[0];
    const int*   labels  = (const int*)d_in[1];
    const float* centers = (const float*)d_in[2];
    float* out = (float*)d_out;

    char* ws = (char*)d_ws;                         // ws is 256 MiB; we use <20 MB
    short* xn   = (short*)(ws + 0);                 // 16384*512 bf16 = 16,777,216 B
    short* cni  = (short*)(ws + 16777216);          //  2880*512 bf16 =  2,949,120 B
    int*   idx  = (int*)(ws + 19726336);            // 90*512 ints    =    184,320 B
    int*   cnt  = (int*)(ws + 19910656);            // 90 ints        =        512 B
    float* pers = (float*)(ws + 19911168);          // 16384 floats   =     65,536 B

    k_norm<<<(BB + NCLS * KC) / 4, 256, 0, stream>>>(x, centers, xn, cni);  // 4816 blocks
    k_bin<<<NCLS, 256, 0, stream>>>(labels, idx, cnt);
    k_main<<<NCLS * 8, 256, 0, stream>>>(xn, cni, cnt, idx, pers);
    k_reduce<<<1, 1024, 0, stream>>>(pers, out);
}

// Round 3
// 36.065 us; speedup vs baseline: 2.2750x; 1.1422x over previous
//
#include <hip/hip_runtime.h>
#include <hip/hip_bf16.h>

// Problem constants (match reference)
#define BB 16384
#define DD 512
#define NCLS 90
#define KC 32
#define BUCKET 512   // max samples per class slot (mean 182, huge headroom)
#define NORMB 720    // center-norm blocks inside k_prep (2880 rows / 4)

typedef __attribute__((ext_vector_type(8))) short short8;   // 8 bf16 (4 VGPRs)
typedef __attribute__((ext_vector_type(4))) float fx4;      // MFMA accumulator

static __device__ __forceinline__ short f2bf(float f) {
    unsigned u = __float_as_uint(f);
    unsigned r = (u + 0x7fffu + ((u >> 16) & 1u)) >> 16;    // RNE
    return (short)r;
}

static __device__ __forceinline__ void gload_lds16(const void* g, void* l) {
    __builtin_amdgcn_global_load_lds(
        (const __attribute__((address_space(1))) void*)g,
        (__attribute__((address_space(3))) void*)l, 16, 0, 0);
}

// ------- kernel 1: prep = center normalize (blocks 0..719) + binning (720..809)
__global__ void k_prep(const float* __restrict__ centers, const int* __restrict__ labels,
                       short* __restrict__ cni, int* __restrict__ idx, int* __restrict__ cnt) {
    if ((int)blockIdx.x < NORMB) {
        // normalize 4 center rows -> bf16 image (one wave per row)
        int row = blockIdx.x * 4 + (threadIdx.x >> 6);      // 0..2879
        int lane = threadIdx.x & 63;
        const float4* p = (const float4*)(centers + (size_t)row * DD);
        float4 a = p[lane * 2];
        float4 b = p[lane * 2 + 1];
        float s = a.x * a.x + a.y * a.y + a.z * a.z + a.w * a.w
                + b.x * b.x + b.y * b.y + b.z * b.z + b.w * b.w;
#pragma unroll
        for (int m = 1; m < 64; m <<= 1) s += __shfl_xor(s, m, 64);
        float sc = rsqrtf(s + 1e-12f);
        short8 v;
        v[0] = f2bf(a.x * sc); v[1] = f2bf(a.y * sc);
        v[2] = f2bf(a.z * sc); v[3] = f2bf(a.w * sc);
        v[4] = f2bf(b.x * sc); v[5] = f2bf(b.y * sc);
        v[6] = f2bf(b.z * sc); v[7] = f2bf(b.w * sc);
        *(short8*)(cni + (size_t)row * DD + lane * 8) = v;
    } else {
        // deterministic ballot-compaction binning, one block per class
        __shared__ int wcnt[4];
        int c = blockIdx.x - NORMB;
        int t = threadIdx.x, w = t >> 6, lane = t & 63;
        int seg = w * (BB / 4);
        int cw = 0;
        for (int j = lane; j < BB / 4; j += 64) cw += (labels[seg + j] == c);
#pragma unroll
        for (int m = 1; m < 64; m <<= 1) cw += __shfl_xor(cw, m, 64);
        if (lane == 0) wcnt[w] = cw;
        __syncthreads();
        int pos = c * BUCKET;
        for (int ww = 0; ww < w; ww++) pos += wcnt[ww];
        for (int j = lane; j < BB / 4; j += 64) {
            bool m = (labels[seg + j] == c);
            unsigned long long mask = __ballot(m);
            if (m) idx[pos + __popcll(mask & ((1ull << lane) - 1ull))] = seg + j;
            pos += __popcll(mask);
        }
        if (t == 0) cnt[c] = wcnt[0] + wcnt[1] + wcnt[2] + wcnt[3];
    }
}

// ------- kernel 2: main — gather raw x, in-flight norm, MFMA, softmax, partial
// grid = 90 classes * 8 p-blocks, block = 256 (4 waves).
// x read ONCE (f32, gathered 2KB rows); norm applied post-MFMA via xinv.
__launch_bounds__(256, 2)
__global__ void k_main(const float* __restrict__ x,
                       const short* __restrict__ cni,
                       const int* __restrict__ cnt,
                       const int* __restrict__ idx,
                       float* __restrict__ partials) {
    __shared__ __align__(16) short c_lds[KC * DD];   // 32 KiB bf16, XOR-swizzled
    __shared__ __align__(16) short x_lds[32 * DD];   // 32 KiB bf16, XOR-swizzled
    __shared__ float S_lds[32][33];
    __shared__ float xinv[32];
    __shared__ float red[256];

    int c = blockIdx.x >> 3;
    int p = blockIdx.x & 7;
    int n = cnt[c];
    int nch = (n + 31) >> 5;
    int t = threadIdx.x, w = t >> 6, lane = t & 63;
    float loss_acc = 0.f;

    if (p < nch) {
        // ---- stage 32 normalized center rows via gload_lds (source-swizzled)
        const short* cbase = cni + (size_t)c * KC * DD;
#pragma unroll
        for (int it = 0; it < 8; it++) {
            int q = t + 256 * it;                 // 16B chunk 0..2047, linear LDS
            int drow = q >> 6, cc = q & 63;
            int scc = cc ^ (drow & 7);
            gload_lds16(cbase + drow * DD + scc * 8, &c_lds[q * 8]);
        }

        int base = c * BUCKET;
        int mrow = ((w & 1) << 4) + (lane & 15);
        int nrow = ((w >> 1) << 4) + (lane & 15);
        int row8 = t >> 3, l8 = t & 7;            // 8 threads per sample row

        for (int ch = p; ch < nch; ch += 8) {
            int off = ch << 5;
            int rem = n - off;                    // > 0

            // ---- gather raw f32 x row, accumulate sq-norm, cvt->bf16 LDS ----
            {
                int r = (row8 < rem) ? row8 : (rem - 1);
                int g = idx[base + off + r];
                const float4* src = (const float4*)(x + (size_t)g * DD);
                float nrm = 0.f;
#pragma unroll
                for (int jj = 0; jj < 8; jj++) {
                    int cc = l8 + 8 * jj;          // 16B bf16 chunk 0..63
                    float4 a = src[cc * 2], b = src[cc * 2 + 1];
                    nrm += a.x * a.x + a.y * a.y + a.z * a.z + a.w * a.w
                         + b.x * b.x + b.y * b.y + b.z * b.z + b.w * b.w;
                    short8 v;
                    v[0] = f2bf(a.x); v[1] = f2bf(a.y); v[2] = f2bf(a.z); v[3] = f2bf(a.w);
                    v[4] = f2bf(b.x); v[5] = f2bf(b.y); v[6] = f2bf(b.z); v[7] = f2bf(b.w);
                    *(short8*)&x_lds[row8 * DD + ((cc ^ (row8 & 7)) << 3)] = v;
                }
#pragma unroll
                for (int m = 1; m < 8; m <<= 1) nrm += __shfl_xor(nrm, m, 64);
                if (l8 == 0) xinv[row8] = rsqrtf(nrm + 1e-12f);
            }
            __syncthreads();

            // ---- MFMA: S[32 samples][32 k] in 4 wave-quadrants ----
            fx4 acc = {0.f, 0.f, 0.f, 0.f};
#pragma unroll
            for (int ks = 0; ks < 16; ks++) {
                int c16a = ks * 4 + (lane >> 4);
                short8 av = *(const short8*)&x_lds[mrow * DD + ((c16a ^ (mrow & 7)) << 3)];
                short8 bv = *(const short8*)&c_lds[nrow * DD + ((c16a ^ (nrow & 7)) << 3)];
                acc = __builtin_amdgcn_mfma_f32_16x16x32_bf16(av, bv, acc, 0, 0, 0);
            }
#pragma unroll
            for (int j = 0; j < 4; j++) {
                int r = ((w & 1) << 4) + ((lane >> 4) << 2) + j;   // C/D row
                int col = ((w >> 1) << 4) + (lane & 15);           // C/D col
                S_lds[r][col] = acc[j];
            }
            __syncthreads();

            // ---- softmax over K=32 + per-sample loss; 8 threads per row ----
            {
                float xv = xinv[row8];
                int q4 = l8 << 2;
                float s0 = S_lds[row8][q4 + 0] * xv;
                float s1 = S_lds[row8][q4 + 1] * xv;
                float s2 = S_lds[row8][q4 + 2] * xv;
                float s3 = S_lds[row8][q4 + 3] * xv;
                float mx = fmaxf(fmaxf(s0, s1), fmaxf(s2, s3));
#pragma unroll
                for (int m = 1; m < 8; m <<= 1) mx = fmaxf(mx, __shfl_xor(mx, m, 64));
                float e0 = expf(s0 - mx), e1 = expf(s1 - mx);
                float e2 = expf(s2 - mx), e3 = expf(s3 - mx);
                float Z = e0 + e1 + e2 + e3;
                float num = e0 * (1.f - s0) + e1 * (1.f - s1)
                          + e2 * (1.f - s2) + e3 * (1.f - s3);
#pragma unroll
                for (int m = 1; m < 8; m <<= 1) {
                    Z += __shfl_xor(Z, m, 64);
                    num += __shfl_xor(num, m, 64);
                }
                if (l8 == 0 && row8 < rem) loss_acc += num / Z;
            }
            __syncthreads();   // protect x_lds/S_lds before next chunk
        }
    }

    // ---- per-block fixed-order partial reduction (inactive blocks emit 0) ----
    red[t] = loss_acc;
    __syncthreads();
    for (int h = 128; h > 0; h >>= 1) {
        if (t < h) red[t] += red[t + h];
        __syncthreads();
    }
    if (t == 0) partials[blockIdx.x] = red[0];
}

// ------- kernel 3: deterministic final mean over 720 block partials ----------
__global__ void k_final(const float* __restrict__ partials, float* __restrict__ out) {
    __shared__ float red[256];
    int t = threadIdx.x;
    float s = 0.f;
    for (int i = t; i < NCLS * 8; i += 256) s += partials[i];
    red[t] = s;
    __syncthreads();
    for (int h = 128; h > 0; h >>= 1) {
        if (t < h) red[t] += red[t + h];
        __syncthreads();
    }
    if (t == 0) out[0] = red[0] * (1.0f / (float)BB);
}

extern "C" void kernel_launch(void* const* d_in, const int* in_sizes, int n_in,
                              void* d_out, int out_size, void* d_ws, size_t ws_size,
                              hipStream_t stream) {
    const float* x       = (const float*)d_in[0];
    const int*   labels  = (const int*)d_in[1];
    const float* centers = (const float*)d_in[2];
    float* out = (float*)d_out;

    char* ws = (char*)d_ws;
    short* cni      = (short*)(ws + 0);             // 2880*512 bf16 = 2,949,120 B
    int*   idx      = (int*)(ws + 3145728);         // 90*512 ints   =   184,320 B
    int*   cnt      = (int*)(ws + 3407872);         // 90 ints
    float* partials = (float*)(ws + 3473408);       // 720 floats

    k_prep<<<NORMB + NCLS, 256, 0, stream>>>(centers, labels, cni, idx, cnt);
    k_main<<<NCLS * 8, 256, 0, stream>>>(x, cni, cnt, idx, partials);
    k_final<<<1, 256, 0, stream>>>(partials, out);
}